// Round 2
// baseline (302.872 us; speedup 1.0000x reference)
//
#include <hip/hip_runtime.h>

#define SEQ 2048
#define DIM 1024

typedef __attribute__((ext_vector_type(8))) __bf16 bf16x8;
typedef __attribute__((ext_vector_type(4))) float f32x4;

typedef __attribute__((address_space(1))) unsigned char gu8_t;
typedef __attribute__((address_space(3))) unsigned char lu8_t;

__device__ __forceinline__ void async_copy16(const void* g, void* l) {
  __builtin_amdgcn_global_load_lds((gu8_t*)g, (lu8_t*)l, 16, 0, 0);
}

__device__ __forceinline__ ushort f2bf(float f) {
  union { float f; unsigned u; } v;
  v.f = f;
  unsigned r = v.u + 0x7FFFu + ((v.u >> 16) & 1u);
  return (ushort)(r >> 16);
}

__global__ void detect_dtype(const unsigned* __restrict__ words,
                             int* __restrict__ flag) {
  const int t = threadIdx.x;
  int hits = 0;
  for (int i = 0; i < 64; i++) {
    const unsigned w = words[t * 64 + i];
    const unsigned b = (w >> 8) & 0x7Fu;
    hits += (b >= 0x3Bu && b <= 0x42u) ? 1 : 0;
  }
#pragma unroll
  for (int o = 32; o > 0; o >>= 1) hits += __shfl_xor(hits, o, 64);
  if (t == 0) *flag = (hits > 2048) ? 1 : 0;
}

__global__ void convert_x(const void* __restrict__ in,
                          ushort* __restrict__ out,
                          const int* __restrict__ flag, int n8) {
  const int i = blockIdx.x * 256 + threadIdx.x;
  if (i >= n8) return;
  if (*flag) {
    reinterpret_cast<uint4*>(out)[i] = reinterpret_cast<const uint4*>(in)[i];
  } else {
    const float4* f = reinterpret_cast<const float4*>(in);
    const float4 a = f[2 * i], b = f[2 * i + 1];
    ushort4 lo, hi;
    lo.x = f2bf(a.x); lo.y = f2bf(a.y); lo.z = f2bf(a.z); lo.w = f2bf(a.w);
    hi.x = f2bf(b.x); hi.y = f2bf(b.y); hi.z = f2bf(b.z); hi.w = f2bf(b.w);
    reinterpret_cast<ushort4*>(out)[2 * i] = lo;
    reinterpret_cast<ushort4*>(out)[2 * i + 1] = hi;
  }
}

__global__ void transpose_w(const void* __restrict__ in,
                            ushort* __restrict__ out,
                            const int* __restrict__ flag) {
  __shared__ ushort tile[64][68];
  const int c0 = blockIdx.x * 64, r0 = blockIdx.y * 64;
  const int t = threadIdx.x;
  if (*flag) {
    const ushort* ip = (const ushort*)in;
#pragma unroll
    for (int i = 0; i < 4; i++) {
      const int lin = i * 256 + t;
      const int r = lin >> 4, c4 = (lin & 15) << 2;
      const ushort4 v = *reinterpret_cast<const ushort4*>(
          ip + (size_t)(r0 + r) * 1024 + c0 + c4);
      tile[r][c4 + 0] = v.x; tile[r][c4 + 1] = v.y;
      tile[r][c4 + 2] = v.z; tile[r][c4 + 3] = v.w;
    }
  } else {
    const float* ip = (const float*)in;
#pragma unroll
    for (int i = 0; i < 4; i++) {
      const int lin = i * 256 + t;
      const int r = lin >> 4, c4 = (lin & 15) << 2;
      const float4 v = *reinterpret_cast<const float4*>(
          ip + (size_t)(r0 + r) * 1024 + c0 + c4);
      tile[r][c4 + 0] = f2bf(v.x); tile[r][c4 + 1] = f2bf(v.y);
      tile[r][c4 + 2] = f2bf(v.z); tile[r][c4 + 3] = f2bf(v.w);
    }
  }
  __syncthreads();
#pragma unroll
  for (int i = 0; i < 4; i++) {
    const int lin = i * 256 + t;
    const int c = lin >> 4, r4 = (lin & 15) << 2;
    ushort4 v;
    v.x = tile[r4 + 0][c]; v.y = tile[r4 + 1][c];
    v.z = tile[r4 + 2][c]; v.w = tile[r4 + 3][c];
    *reinterpret_cast<ushort4*>(out + (size_t)(c0 + c) * 1024 + r0 + r4) = v;
  }
}

__global__ void transpose_bf16(const ushort* __restrict__ in,
                               ushort* __restrict__ out, int R, int C,
                               long inZ, long outZ) {
  __shared__ ushort tile[64][68];
  const ushort* ip = in + (size_t)blockIdx.z * inZ;
  ushort* op = out + (size_t)blockIdx.z * outZ;
  const int c0 = blockIdx.x * 64, r0 = blockIdx.y * 64;
  const int t = threadIdx.x;
#pragma unroll
  for (int i = 0; i < 4; i++) {
    const int lin = i * 256 + t;
    const int r = lin >> 4, c4 = (lin & 15) << 2;
    const ushort4 v =
        *reinterpret_cast<const ushort4*>(ip + (size_t)(r0 + r) * C + c0 + c4);
    tile[r][c4 + 0] = v.x; tile[r][c4 + 1] = v.y;
    tile[r][c4 + 2] = v.z; tile[r][c4 + 3] = v.w;
  }
  __syncthreads();
#pragma unroll
  for (int i = 0; i < 4; i++) {
    const int lin = i * 256 + t;
    const int c = lin >> 4, r4 = (lin & 15) << 2;
    ushort4 v;
    v.x = tile[r4 + 0][c]; v.y = tile[r4 + 1][c];
    v.z = tile[r4 + 2][c]; v.w = tile[r4 + 3][c];
    *reinterpret_cast<ushort4*>(op + (size_t)(c0 + c) * R + r0 + r4) = v;
  }
}

// zBase: absolute batch index of blockIdx.z==0 (for C offset in elements of
// the stored dtype, computed device-side so it works for either dtype).
__global__ __launch_bounds__(256, 2) void gemm_bt(
    const ushort* __restrict__ A, const ushort* __restrict__ Bt,
    void* __restrict__ Cv, const int* __restrict__ flag, int M, int N, int K,
    long aZ, long bZ, long cZ, int zBase, float scale0, float scale1,
    int triSkip, int causalK, int outKind) {
  __shared__ ushort lA[128 * 32];
  __shared__ ushort lB[128 * 32];

  const int n0 = blockIdx.x * 128;
  const int m0 = blockIdx.y * 128;
  if (triSkip && n0 > m0 + 127) return;

  const ushort* Ab = A + (size_t)blockIdx.z * aZ;
  const ushort* Bb = Bt + (size_t)blockIdx.z * bZ;

  const int t = threadIdx.x;
  const int lane = t & 63;
  const int w = t >> 6;
  const int wm = (w >> 1) * 64;
  const int wn = (w & 1) * 64;
  const int quad = lane >> 4;
  const int l15 = lane & 15;

  f32x4 acc[4][4] = {};

  const int kEnd = causalK ? ((m0 + 128 < K) ? (m0 + 128) : K) : K;

  const int idx0 = t;
  const int idx1 = t + 256;
  const int rowA0 = idx0 >> 2, colA0 = (idx0 & 3) << 3;
  const int rowA1 = idx1 >> 2, colA1 = (idx1 & 3) << 3;

  for (int k0 = 0; k0 < kEnd; k0 += 32) {
    __syncthreads();
    async_copy16(Ab + (size_t)(m0 + rowA0) * K + k0 + colA0, lA + idx0 * 8);
    async_copy16(Ab + (size_t)(m0 + rowA1) * K + k0 + colA1, lA + idx1 * 8);
    async_copy16(Bb + (size_t)(n0 + rowA0) * K + k0 + colA0, lB + idx0 * 8);
    async_copy16(Bb + (size_t)(n0 + rowA1) * K + k0 + colA1, lB + idx1 * 8);
    __syncthreads();

    bf16x8 af[4], bfr[4];
#pragma unroll
    for (int mi = 0; mi < 4; mi++)
      af[mi] = *(const bf16x8*)(lA + (wm + mi * 16 + l15) * 32 + quad * 8);
#pragma unroll
    for (int ni = 0; ni < 4; ni++)
      bfr[ni] = *(const bf16x8*)(lB + (wn + ni * 16 + l15) * 32 + quad * 8);
#pragma unroll
    for (int mi = 0; mi < 4; mi++)
#pragma unroll
      for (int ni = 0; ni < 4; ni++)
        acc[mi][ni] = __builtin_amdgcn_mfma_f32_16x16x32_bf16(
            af[mi], bfr[ni], acc[mi][ni], 0, 0, 0);
  }

  const float scale = (blockIdx.z == 0 && zBase == 0) ? scale0 : scale1;
  const bool storeBf = (outKind == 1) || (outKind == 2 && *flag != 0);
  const size_t zc = (size_t)(zBase + blockIdx.z) * cZ;
#pragma unroll
  for (int mi = 0; mi < 4; mi++)
#pragma unroll
    for (int ni = 0; ni < 4; ni++)
#pragma unroll
      for (int r = 0; r < 4; r++) {
        const int row = m0 + wm + mi * 16 + quad * 4 + r;  // col=lane&15,
        const int col = n0 + wn + ni * 16 + l15;           // row=quad*4+r
        const float vv = acc[mi][ni][r] * scale;
        if (storeBf) {
          ushort* C = (ushort*)Cv + zc;
          C[(size_t)row * N + col] = f2bf(vv);
        } else {
          float* C = (float*)Cv + zc;
          C[(size_t)row * N + col] = vv;
        }
      }
}

__global__ void softmax_causal(const float* __restrict__ Sc,
                               ushort* __restrict__ P) {
  const int rid = blockIdx.x;
  const int i = rid & (SEQ - 1);
  const float* row = Sc + (size_t)rid * SEQ;
  ushort* prow = P + (size_t)rid * SEQ;
  const int t = threadIdx.x;
  __shared__ float red[4];

  float mx = -3.0e38f;
  for (int j = t; j <= i; j += 256) mx = fmaxf(mx, row[j]);
#pragma unroll
  for (int o = 32; o > 0; o >>= 1) mx = fmaxf(mx, __shfl_xor(mx, o, 64));
  if ((t & 63) == 0) red[t >> 6] = mx;
  __syncthreads();
  mx = fmaxf(fmaxf(red[0], red[1]), fmaxf(red[2], red[3]));
  __syncthreads();

  float sum = 0.0f;
  for (int j = t; j <= i; j += 256) sum += __expf(row[j] - mx);
#pragma unroll
  for (int o = 32; o > 0; o >>= 1) sum += __shfl_xor(sum, o, 64);
  if ((t & 63) == 0) red[t >> 6] = sum;
  __syncthreads();
  sum = red[0] + red[1] + red[2] + red[3];
  const float inv = 1.0f / sum;

  for (int j = t; j < SEQ; j += 256) {
    const float v = (j <= i) ? __expf(row[j] - mx) * inv : 0.0f;
    prow[j] = f2bf(v);
  }
}

extern "C" void kernel_launch(void* const* d_in, const int* in_sizes, int n_in,
                              void* d_out, int out_size, void* d_ws,
                              size_t ws_size, hipStream_t stream) {
  char* ws = (char*)d_ws;
  const size_t MB = 1024 * 1024;
  int* flag = (int*)ws;
  ushort* wt = (ushort*)(ws + 1 * MB);
  ushort* xb = (ushort*)(ws + 7 * MB);
  ushort* q = (ushort*)(ws + 23 * MB);
  ushort* kk = (ushort*)(ws + 39 * MB);
  ushort* v = (ushort*)(ws + 55 * MB);
  ushort* vt = (ushort*)(ws + 71 * MB);
  float* sc = (float*)(ws + 87 * MB);

  int g = 4;
  while (g > 1 && (87 + 24 * (size_t)g) * MB > ws_size) g >>= 1;
  ushort* p = (ushort*)(ws + (87 + 16 * (size_t)g) * MB);
  (void)kk;

  detect_dtype<<<dim3(1), 64, 0, stream>>>((const unsigned*)d_in[0], flag);

  convert_x<<<dim3(4096), 256, 0, stream>>>(d_in[0], xb, flag,
                                            (8192 * 1024) / 8);

  for (int i = 0; i < 3; i++)
    transpose_w<<<dim3(16, 16), 256, 0, stream>>>(
        d_in[1 + i], wt + (size_t)i * 1024 * 1024, flag);

  // QKV projections: z=0 -> Q (scaled 1/sqrt(1024)=1/32), z=1 -> K, z=2 -> V
  gemm_bt<<<dim3(8, 64, 3), 256, 0, stream>>>(
      xb, wt, (void*)q, flag, 8192, 1024, 1024, 0L, (long)1024 * 1024,
      (long)8192 * 1024, 0, 0.03125f, 1.0f, 0, 0, 1);

  transpose_bf16<<<dim3(16, 32, 4), 256, 0, stream>>>(
      v, vt, 2048, 1024, (long)SEQ * DIM, (long)DIM * SEQ);

  for (int b0 = 0; b0 < 4; b0 += g) {
    gemm_bt<<<dim3(16, 16, g), 256, 0, stream>>>(
        q + (size_t)b0 * SEQ * DIM, kk + (size_t)b0 * SEQ * DIM, (void*)sc,
        flag, 2048, 2048, 1024, (long)SEQ * DIM, (long)SEQ * DIM,
        (long)SEQ * SEQ, 0, 1.0f, 1.0f, 1, 0, 0);
    softmax_causal<<<dim3(g * SEQ), 256, 0, stream>>>(sc, p);
    // out = P * V^T; C batch offset = (b0+z)*SEQ*DIM elements of stored dtype
    gemm_bt<<<dim3(8, 16, g), 256, 0, stream>>>(
        p, vt + (size_t)b0 * DIM * SEQ, d_out, flag, 2048, 1024, 2048,
        (long)SEQ * SEQ, (long)DIM * SEQ, (long)SEQ * DIM, b0, 1.0f, 1.0f, 0,
        1, 2);
  }
}

// Round 3
// 290.106 us; speedup vs baseline: 1.0440x; 1.0440x over previous
//
#include <hip/hip_runtime.h>

#define SEQ 2048
#define DIM 1024

typedef __attribute__((ext_vector_type(8))) __bf16 bf16x8;
typedef __attribute__((ext_vector_type(4))) float f32x4;

typedef __attribute__((address_space(1))) unsigned char gu8_t;
typedef __attribute__((address_space(3))) unsigned char lu8_t;

__device__ __forceinline__ void async_copy16(const void* g, void* l) {
  __builtin_amdgcn_global_load_lds((gu8_t*)g, (lu8_t*)l, 16, 0, 0);
}

__device__ __forceinline__ ushort f2bf(float f) {
  union { float f; unsigned u; } v;
  v.f = f;
  unsigned r = v.u + 0x7FFFu + ((v.u >> 16) & 1u);
  return (ushort)(r >> 16);
}

__global__ void detect_dtype(const unsigned* __restrict__ words,
                             int* __restrict__ flag) {
  const int t = threadIdx.x;
  int hits = 0;
  for (int i = 0; i < 64; i++) {
    const unsigned w = words[t * 64 + i];
    const unsigned b = (w >> 8) & 0x7Fu;
    hits += (b >= 0x3Bu && b <= 0x42u) ? 1 : 0;
  }
#pragma unroll
  for (int o = 32; o > 0; o >>= 1) hits += __shfl_xor(hits, o, 64);
  if (t == 0) *flag = (hits > 2048) ? 1 : 0;
}

__global__ void convert_x(const void* __restrict__ in,
                          ushort* __restrict__ out,
                          const int* __restrict__ flag, int n8) {
  const int i = blockIdx.x * 256 + threadIdx.x;
  if (i >= n8) return;
  if (*flag) {
    reinterpret_cast<uint4*>(out)[i] = reinterpret_cast<const uint4*>(in)[i];
  } else {
    const float4* f = reinterpret_cast<const float4*>(in);
    const float4 a = f[2 * i], b = f[2 * i + 1];
    ushort4 lo, hi;
    lo.x = f2bf(a.x); lo.y = f2bf(a.y); lo.z = f2bf(a.z); lo.w = f2bf(a.w);
    hi.x = f2bf(b.x); hi.y = f2bf(b.y); hi.z = f2bf(b.z); hi.w = f2bf(b.w);
    reinterpret_cast<ushort4*>(out)[2 * i] = lo;
    reinterpret_cast<ushort4*>(out)[2 * i + 1] = hi;
  }
}

__global__ void transpose_w(const void* __restrict__ in,
                            ushort* __restrict__ out,
                            const int* __restrict__ flag) {
  __shared__ ushort tile[64][68];
  const int c0 = blockIdx.x * 64, r0 = blockIdx.y * 64;
  const int t = threadIdx.x;
  if (*flag) {
    const ushort* ip = (const ushort*)in;
#pragma unroll
    for (int i = 0; i < 4; i++) {
      const int lin = i * 256 + t;
      const int r = lin >> 4, c4 = (lin & 15) << 2;
      const ushort4 v = *reinterpret_cast<const ushort4*>(
          ip + (size_t)(r0 + r) * 1024 + c0 + c4);
      tile[r][c4 + 0] = v.x; tile[r][c4 + 1] = v.y;
      tile[r][c4 + 2] = v.z; tile[r][c4 + 3] = v.w;
    }
  } else {
    const float* ip = (const float*)in;
#pragma unroll
    for (int i = 0; i < 4; i++) {
      const int lin = i * 256 + t;
      const int r = lin >> 4, c4 = (lin & 15) << 2;
      const float4 v = *reinterpret_cast<const float4*>(
          ip + (size_t)(r0 + r) * 1024 + c0 + c4);
      tile[r][c4 + 0] = f2bf(v.x); tile[r][c4 + 1] = f2bf(v.y);
      tile[r][c4 + 2] = f2bf(v.z); tile[r][c4 + 3] = f2bf(v.w);
    }
  }
  __syncthreads();
#pragma unroll
  for (int i = 0; i < 4; i++) {
    const int lin = i * 256 + t;
    const int c = lin >> 4, r4 = (lin & 15) << 2;
    ushort4 v;
    v.x = tile[r4 + 0][c]; v.y = tile[r4 + 1][c];
    v.z = tile[r4 + 2][c]; v.w = tile[r4 + 3][c];
    *reinterpret_cast<ushort4*>(out + (size_t)(c0 + c) * 1024 + r0 + r4) = v;
  }
}

__global__ void transpose_bf16(const ushort* __restrict__ in,
                               ushort* __restrict__ out, int R, int C,
                               long inZ, long outZ) {
  __shared__ ushort tile[64][68];
  const ushort* ip = in + (size_t)blockIdx.z * inZ;
  ushort* op = out + (size_t)blockIdx.z * outZ;
  const int c0 = blockIdx.x * 64, r0 = blockIdx.y * 64;
  const int t = threadIdx.x;
#pragma unroll
  for (int i = 0; i < 4; i++) {
    const int lin = i * 256 + t;
    const int r = lin >> 4, c4 = (lin & 15) << 2;
    const ushort4 v =
        *reinterpret_cast<const ushort4*>(ip + (size_t)(r0 + r) * C + c0 + c4);
    tile[r][c4 + 0] = v.x; tile[r][c4 + 1] = v.y;
    tile[r][c4 + 2] = v.z; tile[r][c4 + 3] = v.w;
  }
  __syncthreads();
#pragma unroll
  for (int i = 0; i < 4; i++) {
    const int lin = i * 256 + t;
    const int c = lin >> 4, r4 = (lin & 15) << 2;
    ushort4 v;
    v.x = tile[r4 + 0][c]; v.y = tile[r4 + 1][c];
    v.z = tile[r4 + 2][c]; v.w = tile[r4 + 3][c];
    *reinterpret_cast<ushort4*>(op + (size_t)(c0 + c) * R + r0 + r4) = v;
  }
}

// zBase: absolute batch index of blockIdx.z==0 (C offset in elements of the
// stored dtype, applied device-side so it works for either output dtype).
// launch_bounds(256,4): VGPR+AGPR fits in 120 <= 128 -> 4 blocks/CU resident.
__global__ __launch_bounds__(256, 4) void gemm_bt(
    const ushort* __restrict__ A, const ushort* __restrict__ Bt,
    void* __restrict__ Cv, const int* __restrict__ flag, int M, int N, int K,
    long aZ, long bZ, long cZ, int zBase, float scale0, float scale1,
    int triSkip, int causalK, int outKind) {
  __shared__ ushort lA[128 * 32];
  __shared__ ushort lB[128 * 32];

  const int n0 = blockIdx.x * 128;
  const int m0 = blockIdx.y * 128;
  if (triSkip && n0 > m0 + 127) return;

  const ushort* Ab = A + (size_t)blockIdx.z * aZ;
  const ushort* Bb = Bt + (size_t)blockIdx.z * bZ;

  const int t = threadIdx.x;
  const int lane = t & 63;
  const int w = t >> 6;
  const int wm = (w >> 1) * 64;
  const int wn = (w & 1) * 64;
  const int quad = lane >> 4;
  const int l15 = lane & 15;

  f32x4 acc[4][4] = {};

  const int kEnd = causalK ? ((m0 + 128 < K) ? (m0 + 128) : K) : K;

  const int idx0 = t;
  const int idx1 = t + 256;
  const int rowA0 = idx0 >> 2, colA0 = (idx0 & 3) << 3;
  const int rowA1 = idx1 >> 2, colA1 = (idx1 & 3) << 3;

  for (int k0 = 0; k0 < kEnd; k0 += 32) {
    __syncthreads();
    async_copy16(Ab + (size_t)(m0 + rowA0) * K + k0 + colA0, lA + idx0 * 8);
    async_copy16(Ab + (size_t)(m0 + rowA1) * K + k0 + colA1, lA + idx1 * 8);
    async_copy16(Bb + (size_t)(n0 + rowA0) * K + k0 + colA0, lB + idx0 * 8);
    async_copy16(Bb + (size_t)(n0 + rowA1) * K + k0 + colA1, lB + idx1 * 8);
    __syncthreads();

    bf16x8 af[4], bfr[4];
#pragma unroll
    for (int mi = 0; mi < 4; mi++)
      af[mi] = *(const bf16x8*)(lA + (wm + mi * 16 + l15) * 32 + quad * 8);
#pragma unroll
    for (int ni = 0; ni < 4; ni++)
      bfr[ni] = *(const bf16x8*)(lB + (wn + ni * 16 + l15) * 32 + quad * 8);
#pragma unroll
    for (int mi = 0; mi < 4; mi++)
#pragma unroll
      for (int ni = 0; ni < 4; ni++)
        acc[mi][ni] = __builtin_amdgcn_mfma_f32_16x16x32_bf16(
            af[mi], bfr[ni], acc[mi][ni], 0, 0, 0);
  }

  const float scale = (blockIdx.z == 0 && zBase == 0) ? scale0 : scale1;
  const bool storeBf = (outKind == 1) || (outKind == 2 && *flag != 0);
  const size_t zc = (size_t)(zBase + blockIdx.z) * cZ;
#pragma unroll
  for (int mi = 0; mi < 4; mi++)
#pragma unroll
    for (int ni = 0; ni < 4; ni++)
#pragma unroll
      for (int r = 0; r < 4; r++) {
        const int row = m0 + wm + mi * 16 + quad * 4 + r;  // col=lane&15,
        const int col = n0 + wn + ni * 16 + l15;           // row=quad*4+r
        const float vv = acc[mi][ni][r] * scale;
        if (storeBf) {
          ushort* C = (ushort*)Cv + zc;
          C[(size_t)row * N + col] = f2bf(vv);
        } else {
          float* C = (float*)Cv + zc;
          C[(size_t)row * N + col] = vv;
        }
      }
}

// Causal softmax: row cached in 8 regs/thread -> 1 global read pass, 1 expf.
// Masked entries become exp(-3e38 - mx) == 0, so the store is branchless.
__global__ void softmax_causal(const float* __restrict__ Sc,
                               ushort* __restrict__ P) {
  const int rid = blockIdx.x;
  const int i = rid & (SEQ - 1);
  const float* row = Sc + (size_t)rid * SEQ;
  ushort* prow = P + (size_t)rid * SEQ;
  const int t = threadIdx.x;
  __shared__ float red[4];

  float r[8];
  float mx = -3.0e38f;
#pragma unroll
  for (int it = 0; it < 8; it++) {
    const int j = it * 256 + t;
    r[it] = (j <= i) ? row[j] : -3.0e38f;
    mx = fmaxf(mx, r[it]);
  }
#pragma unroll
  for (int o = 32; o > 0; o >>= 1) mx = fmaxf(mx, __shfl_xor(mx, o, 64));
  if ((t & 63) == 0) red[t >> 6] = mx;
  __syncthreads();
  mx = fmaxf(fmaxf(red[0], red[1]), fmaxf(red[2], red[3]));
  __syncthreads();

  float sum = 0.0f;
#pragma unroll
  for (int it = 0; it < 8; it++) {
    r[it] = __expf(r[it] - mx);  // masked: exp(-inf) = 0
    sum += r[it];
  }
#pragma unroll
  for (int o = 32; o > 0; o >>= 1) sum += __shfl_xor(sum, o, 64);
  if ((t & 63) == 0) red[t >> 6] = sum;
  __syncthreads();
  sum = red[0] + red[1] + red[2] + red[3];
  const float inv = 1.0f / sum;

#pragma unroll
  for (int it = 0; it < 8; it++) {
    const int j = it * 256 + t;
    prow[j] = f2bf(r[it] * inv);
  }
}

extern "C" void kernel_launch(void* const* d_in, const int* in_sizes, int n_in,
                              void* d_out, int out_size, void* d_ws,
                              size_t ws_size, hipStream_t stream) {
  char* ws = (char*)d_ws;
  const size_t MB = 1024 * 1024;
  int* flag = (int*)ws;
  ushort* wt = (ushort*)(ws + 1 * MB);
  ushort* xb = (ushort*)(ws + 7 * MB);
  ushort* q = (ushort*)(ws + 23 * MB);
  ushort* kk = (ushort*)(ws + 39 * MB);
  ushort* v = (ushort*)(ws + 55 * MB);
  ushort* vt = (ushort*)(ws + 71 * MB);
  float* sc = (float*)(ws + 87 * MB);

  int g = 4;
  while (g > 1 && (87 + 24 * (size_t)g) * MB > ws_size) g >>= 1;
  ushort* p = (ushort*)(ws + (87 + 16 * (size_t)g) * MB);
  (void)kk;

  detect_dtype<<<dim3(1), 64, 0, stream>>>((const unsigned*)d_in[0], flag);

  convert_x<<<dim3(4096), 256, 0, stream>>>(d_in[0], xb, flag,
                                            (8192 * 1024) / 8);

  for (int i = 0; i < 3; i++)
    transpose_w<<<dim3(16, 16), 256, 0, stream>>>(
        d_in[1 + i], wt + (size_t)i * 1024 * 1024, flag);

  // QKV projections: z=0 -> Q (scaled 1/sqrt(1024)=1/32), z=1 -> K, z=2 -> V
  gemm_bt<<<dim3(8, 64, 3), 256, 0, stream>>>(
      xb, wt, (void*)q, flag, 8192, 1024, 1024, 0L, (long)1024 * 1024,
      (long)8192 * 1024, 0, 0.03125f, 1.0f, 0, 0, 1);

  transpose_bf16<<<dim3(16, 32, 4), 256, 0, stream>>>(
      v, vt, 2048, 1024, (long)SEQ * DIM, (long)DIM * SEQ);

  for (int b0 = 0; b0 < 4; b0 += g) {
    gemm_bt<<<dim3(16, 16, g), 256, 0, stream>>>(
        q + (size_t)b0 * SEQ * DIM, kk + (size_t)b0 * SEQ * DIM, (void*)sc,
        flag, 2048, 2048, 1024, (long)SEQ * DIM, (long)SEQ * DIM,
        (long)SEQ * SEQ, 0, 1.0f, 1.0f, 1, 0, 0);
    softmax_causal<<<dim3(g * SEQ), 256, 0, stream>>>(sc, p);
    gemm_bt<<<dim3(8, 16, g), 256, 0, stream>>>(
        p, vt + (size_t)b0 * DIM * SEQ, d_out, flag, 2048, 1024, 2048,
        (long)SEQ * SEQ, (long)DIM * SEQ, (long)SEQ * DIM, b0, 1.0f, 1.0f, 0,
        1, 2);
  }
}

// Round 4
// 274.940 us; speedup vs baseline: 1.1016x; 1.0552x over previous
//
#include <hip/hip_runtime.h>

#define SEQ 2048
#define DIM 1024

typedef __attribute__((ext_vector_type(8))) __bf16 bf16x8;
typedef __attribute__((ext_vector_type(4))) float f32x4;

typedef __attribute__((address_space(1))) unsigned char gu8_t;
typedef __attribute__((address_space(3))) unsigned char lu8_t;

__device__ __forceinline__ void async_copy16(const void* g, void* l) {
  __builtin_amdgcn_global_load_lds((gu8_t*)g, (lu8_t*)l, 16, 0, 0);
}

__device__ __forceinline__ ushort f2bf(float f) {
  union { float f; unsigned u; } v;
  v.f = f;
  unsigned r = v.u + 0x7FFFu + ((v.u >> 16) & 1u);
  return (ushort)(r >> 16);
}

__global__ void detect_dtype(const unsigned* __restrict__ words,
                             int* __restrict__ flag) {
  const int t = threadIdx.x;
  int hits = 0;
  for (int i = 0; i < 64; i++) {
    const unsigned w = words[t * 64 + i];
    const unsigned b = (w >> 8) & 0x7Fu;
    hits += (b >= 0x3Bu && b <= 0x42u) ? 1 : 0;
  }
#pragma unroll
  for (int o = 32; o > 0; o >>= 1) hits += __shfl_xor(hits, o, 64);
  if (t == 0) *flag = (hits > 2048) ? 1 : 0;
}

__global__ void convert_x(const void* __restrict__ in,
                          ushort* __restrict__ out,
                          const int* __restrict__ flag, int n8) {
  const int i = blockIdx.x * 256 + threadIdx.x;
  if (i >= n8) return;
  if (*flag) {
    reinterpret_cast<uint4*>(out)[i] = reinterpret_cast<const uint4*>(in)[i];
  } else {
    const float4* f = reinterpret_cast<const float4*>(in);
    const float4 a = f[2 * i], b = f[2 * i + 1];
    ushort4 lo, hi;
    lo.x = f2bf(a.x); lo.y = f2bf(a.y); lo.z = f2bf(a.z); lo.w = f2bf(a.w);
    hi.x = f2bf(b.x); hi.y = f2bf(b.y); hi.z = f2bf(b.z); hi.w = f2bf(b.w);
    reinterpret_cast<ushort4*>(out)[2 * i] = lo;
    reinterpret_cast<ushort4*>(out)[2 * i + 1] = hi;
  }
}

// All 3 weight matrices in one launch (z selects the input pointer).
__global__ void transpose_w(const void* __restrict__ w0,
                            const void* __restrict__ w1,
                            const void* __restrict__ w2,
                            ushort* __restrict__ out,
                            const int* __restrict__ flag) {
  __shared__ ushort tile[64][68];
  const int z = blockIdx.z;
  const void* in = (z == 0) ? w0 : (z == 1) ? w1 : w2;
  ushort* op = out + (size_t)z * 1024 * 1024;
  const int c0 = blockIdx.x * 64, r0 = blockIdx.y * 64;
  const int t = threadIdx.x;
  if (*flag) {
    const ushort* ip = (const ushort*)in;
#pragma unroll
    for (int i = 0; i < 4; i++) {
      const int lin = i * 256 + t;
      const int r = lin >> 4, c4 = (lin & 15) << 2;
      const ushort4 v = *reinterpret_cast<const ushort4*>(
          ip + (size_t)(r0 + r) * 1024 + c0 + c4);
      tile[r][c4 + 0] = v.x; tile[r][c4 + 1] = v.y;
      tile[r][c4 + 2] = v.z; tile[r][c4 + 3] = v.w;
    }
  } else {
    const float* ip = (const float*)in;
#pragma unroll
    for (int i = 0; i < 4; i++) {
      const int lin = i * 256 + t;
      const int r = lin >> 4, c4 = (lin & 15) << 2;
      const float4 v = *reinterpret_cast<const float4*>(
          ip + (size_t)(r0 + r) * 1024 + c0 + c4);
      tile[r][c4 + 0] = f2bf(v.x); tile[r][c4 + 1] = f2bf(v.y);
      tile[r][c4 + 2] = f2bf(v.z); tile[r][c4 + 3] = f2bf(v.w);
    }
  }
  __syncthreads();
#pragma unroll
  for (int i = 0; i < 4; i++) {
    const int lin = i * 256 + t;
    const int c = lin >> 4, r4 = (lin & 15) << 2;
    ushort4 v;
    v.x = tile[r4 + 0][c]; v.y = tile[r4 + 1][c];
    v.z = tile[r4 + 2][c]; v.w = tile[r4 + 3][c];
    *reinterpret_cast<ushort4*>(op + (size_t)(c0 + c) * 1024 + r0 + r4) = v;
  }
}

__global__ void transpose_bf16(const ushort* __restrict__ in,
                               ushort* __restrict__ out, int R, int C,
                               long inZ, long outZ) {
  __shared__ ushort tile[64][68];
  const ushort* ip = in + (size_t)blockIdx.z * inZ;
  ushort* op = out + (size_t)blockIdx.z * outZ;
  const int c0 = blockIdx.x * 64, r0 = blockIdx.y * 64;
  const int t = threadIdx.x;
#pragma unroll
  for (int i = 0; i < 4; i++) {
    const int lin = i * 256 + t;
    const int r = lin >> 4, c4 = (lin & 15) << 2;
    const ushort4 v =
        *reinterpret_cast<const ushort4*>(ip + (size_t)(r0 + r) * C + c0 + c4);
    tile[r][c4 + 0] = v.x; tile[r][c4 + 1] = v.y;
    tile[r][c4 + 2] = v.z; tile[r][c4 + 3] = v.w;
  }
  __syncthreads();
#pragma unroll
  for (int i = 0; i < 4; i++) {
    const int lin = i * 256 + t;
    const int c = lin >> 4, r4 = (lin & 15) << 2;
    ushort4 v;
    v.x = tile[r4 + 0][c]; v.y = tile[r4 + 1][c];
    v.z = tile[r4 + 2][c]; v.w = tile[r4 + 3][c];
    *reinterpret_cast<ushort4*>(op + (size_t)(c0 + c) * R + r0 + r4) = v;
  }
}

// XCD-aware swizzle: flat id's %8 residue picks the XCD (round-robin
// dispatch), so give each residue a fixed 1/8 slice of the m-tiles with all
// n-tiles consecutive. A-tile then stays in that XCD's L2 across its n-group
// (2MB << 4MB), B-slice likewise. Requires gridDim.y % 8 == 0.
__global__ __launch_bounds__(256, 4) void gemm_bt(
    const ushort* __restrict__ A, const ushort* __restrict__ Bt,
    void* __restrict__ Cv, const int* __restrict__ flag, int M, int N, int K,
    long aZ, long bZ, long cZ, int zBase, float scale0, float scale1,
    int triSkip, int causalK, int outKind) {
  __shared__ ushort lA[128 * 32];
  __shared__ ushort lB[128 * 32];

  const int nT = gridDim.x;
  const int id = blockIdx.y * nT + blockIdx.x;
  const int xcd = id & 7;
  const int loc = id >> 3;
  const int n0 = (loc % nT) * 128;
  const int m0 = (xcd + ((loc / nT) << 3)) * 128;
  if (triSkip && n0 > m0 + 127) return;

  const ushort* Ab = A + (size_t)blockIdx.z * aZ;
  const ushort* Bb = Bt + (size_t)blockIdx.z * bZ;

  const int t = threadIdx.x;
  const int lane = t & 63;
  const int w = t >> 6;
  const int wm = (w >> 1) * 64;
  const int wn = (w & 1) * 64;
  const int quad = lane >> 4;
  const int l15 = lane & 15;

  f32x4 acc[4][4] = {};

  const int kEnd = causalK ? ((m0 + 128 < K) ? (m0 + 128) : K) : K;

  const int idx0 = t;
  const int idx1 = t + 256;
  const int rowA0 = idx0 >> 2, colA0 = (idx0 & 3) << 3;
  const int rowA1 = idx1 >> 2, colA1 = (idx1 & 3) << 3;

  for (int k0 = 0; k0 < kEnd; k0 += 32) {
    __syncthreads();
    async_copy16(Ab + (size_t)(m0 + rowA0) * K + k0 + colA0, lA + idx0 * 8);
    async_copy16(Ab + (size_t)(m0 + rowA1) * K + k0 + colA1, lA + idx1 * 8);
    async_copy16(Bb + (size_t)(n0 + rowA0) * K + k0 + colA0, lB + idx0 * 8);
    async_copy16(Bb + (size_t)(n0 + rowA1) * K + k0 + colA1, lB + idx1 * 8);
    __syncthreads();

    bf16x8 af[4], bfr[4];
#pragma unroll
    for (int mi = 0; mi < 4; mi++)
      af[mi] = *(const bf16x8*)(lA + (wm + mi * 16 + l15) * 32 + quad * 8);
#pragma unroll
    for (int ni = 0; ni < 4; ni++)
      bfr[ni] = *(const bf16x8*)(lB + (wn + ni * 16 + l15) * 32 + quad * 8);
#pragma unroll
    for (int mi = 0; mi < 4; mi++)
#pragma unroll
      for (int ni = 0; ni < 4; ni++)
        acc[mi][ni] = __builtin_amdgcn_mfma_f32_16x16x32_bf16(
            af[mi], bfr[ni], acc[mi][ni], 0, 0, 0);
  }

  const float scale = (blockIdx.z == 0 && zBase == 0) ? scale0 : scale1;
  const bool storeBf = (outKind == 1) || (outKind == 2 && *flag != 0);
  const size_t zc = (size_t)(zBase + blockIdx.z) * cZ;
#pragma unroll
  for (int mi = 0; mi < 4; mi++)
#pragma unroll
    for (int ni = 0; ni < 4; ni++)
#pragma unroll
      for (int r = 0; r < 4; r++) {
        const int row = m0 + wm + mi * 16 + quad * 4 + r;  // col=lane&15,
        const int col = n0 + wn + ni * 16 + l15;           // row=quad*4+r
        const float vv = acc[mi][ni][r] * scale;
        if (storeBf) {
          ushort* C = (ushort*)Cv + zc;
          C[(size_t)row * N + col] = f2bf(vv);
        } else {
          float* C = (float*)Cv + zc;
          C[(size_t)row * N + col] = vv;
        }
      }
}

// Causal softmax: row cached in 8 regs/thread -> 1 global read pass, 1 expf.
__global__ void softmax_causal(const float* __restrict__ Sc,
                               ushort* __restrict__ P) {
  const int rid = blockIdx.x;
  const int i = rid & (SEQ - 1);
  const float* row = Sc + (size_t)rid * SEQ;
  ushort* prow = P + (size_t)rid * SEQ;
  const int t = threadIdx.x;
  __shared__ float red[4];

  float r[8];
  float mx = -3.0e38f;
#pragma unroll
  for (int it = 0; it < 8; it++) {
    const int j = it * 256 + t;
    r[it] = (j <= i) ? row[j] : -3.0e38f;
    mx = fmaxf(mx, r[it]);
  }
#pragma unroll
  for (int o = 32; o > 0; o >>= 1) mx = fmaxf(mx, __shfl_xor(mx, o, 64));
  if ((t & 63) == 0) red[t >> 6] = mx;
  __syncthreads();
  mx = fmaxf(fmaxf(red[0], red[1]), fmaxf(red[2], red[3]));
  __syncthreads();

  float sum = 0.0f;
#pragma unroll
  for (int it = 0; it < 8; it++) {
    r[it] = __expf(r[it] - mx);
    sum += r[it];
  }
#pragma unroll
  for (int o = 32; o > 0; o >>= 1) sum += __shfl_xor(sum, o, 64);
  if ((t & 63) == 0) red[t >> 6] = sum;
  __syncthreads();
  sum = red[0] + red[1] + red[2] + red[3];
  const float inv = 1.0f / sum;

#pragma unroll
  for (int it = 0; it < 8; it++) {
    const int j = it * 256 + t;
    prow[j] = f2bf(r[it] * inv);
  }
}

extern "C" void kernel_launch(void* const* d_in, const int* in_sizes, int n_in,
                              void* d_out, int out_size, void* d_ws,
                              size_t ws_size, hipStream_t stream) {
  char* ws = (char*)d_ws;
  const size_t MB = 1024 * 1024;
  int* flag = (int*)ws;
  ushort* wt = (ushort*)(ws + 1 * MB);
  ushort* xb = (ushort*)(ws + 7 * MB);
  ushort* q = (ushort*)(ws + 23 * MB);
  ushort* kk = (ushort*)(ws + 39 * MB);
  ushort* v = (ushort*)(ws + 55 * MB);
  ushort* vt = (ushort*)(ws + 71 * MB);
  float* sc = (float*)(ws + 87 * MB);

  int g = 4;
  while (g > 1 && (87 + 24 * (size_t)g) * MB > ws_size) g >>= 1;
  ushort* p = (ushort*)(ws + (87 + 16 * (size_t)g) * MB);
  (void)kk;

  detect_dtype<<<dim3(1), 64, 0, stream>>>((const unsigned*)d_in[0], flag);

  convert_x<<<dim3(4096), 256, 0, stream>>>(d_in[0], xb, flag,
                                            (8192 * 1024) / 8);

  transpose_w<<<dim3(16, 16, 3), 256, 0, stream>>>(d_in[1], d_in[2], d_in[3],
                                                   wt, flag);

  // QKV projections: z=0 -> Q (scaled 1/sqrt(1024)=1/32), z=1 -> K, z=2 -> V
  gemm_bt<<<dim3(8, 64, 3), 256, 0, stream>>>(
      xb, wt, (void*)q, flag, 8192, 1024, 1024, 0L, (long)1024 * 1024,
      (long)8192 * 1024, 0, 0.03125f, 1.0f, 0, 0, 1);

  transpose_bf16<<<dim3(16, 32, 4), 256, 0, stream>>>(
      v, vt, 2048, 1024, (long)SEQ * DIM, (long)DIM * SEQ);

  for (int b0 = 0; b0 < 4; b0 += g) {
    gemm_bt<<<dim3(16, 16, g), 256, 0, stream>>>(
        q + (size_t)b0 * SEQ * DIM, kk + (size_t)b0 * SEQ * DIM, (void*)sc,
        flag, 2048, 2048, 1024, (long)SEQ * DIM, (long)SEQ * DIM,
        (long)SEQ * SEQ, 0, 1.0f, 1.0f, 1, 0, 0);
    softmax_causal<<<dim3(g * SEQ), 256, 0, stream>>>(sc, p);
    gemm_bt<<<dim3(8, 16, g), 256, 0, stream>>>(
        p, vt + (size_t)b0 * DIM * SEQ, d_out, flag, 2048, 1024, 2048,
        (long)SEQ * SEQ, (long)DIM * SEQ, (long)SEQ * DIM, b0, 1.0f, 1.0f, 0,
        1, 2);
  }
}